// Round 8
// baseline (168.262 us; speedup 1.0000x reference)
//
#include <hip/hip_runtime.h>

// Integrator (scaling & squaring) for vel [16,2,512,512] f32, with logdet-Jacobian.
// FP16 intermediates (disp interleaved [N,HW,2] half2, ldjac [N,HW] half),
// XCD-remapped steps, ping-pong. ROUND-8 change: 2 px/thread (x,x+1) in steps
// -> two independent gather chains per thread (2x MLP), vectorized streaming
// loads/stores, halved wave count. Per-pixel math identical to round 7.
// Scratch sets: A = d_out raw bytes (24MB of 48MB), B = ws (24MB).

#define NB 16
#define HH 512
#define WW 512
#define HW (HH * WW)          // 262144 = 1<<18
#define TOT (NB * HW)         // 4194304
#define EPS 0.0078125f        // 2^-7
#define DISP_ELEMS (NB * 2 * HW)   // 8388608 (f32 elems of final planar disp)
#define SC (512.0f / 511.0f)

typedef _Float16 f16;
typedef _Float16 f16x2 __attribute__((ext_vector_type(2)));
typedef _Float16 f16x4 __attribute__((ext_vector_type(4)));
typedef float f32x2 __attribute__((ext_vector_type(2)));

struct Samp {
    int i00, i01, i10, i11;   // clamped plane offsets (y*W+x)
    float w00, w01, w10, w11; // bilinear weights with OOB folded to 0
};

__device__ __forceinline__ Samp make_samp(float sy, float sx) {
    float fy = floorf(sy), fx = floorf(sx);
    float wy = sy - fy, wx = sx - fx;
    int y0 = (int)fy, x0 = (int)fx;
    int y1 = y0 + 1, x1 = x0 + 1;
    bool xv0 = (unsigned)x0 < (unsigned)WW;
    bool xv1 = (unsigned)x1 < (unsigned)WW;
    bool yv0 = (unsigned)y0 < (unsigned)HH;
    bool yv1 = (unsigned)y1 < (unsigned)HH;
    int xc0 = min(max(x0, 0), WW - 1), xc1 = min(max(x1, 0), WW - 1);
    int yc0 = min(max(y0, 0), HH - 1), yc1 = min(max(y1, 0), HH - 1);
    Samp s;
    s.i00 = yc0 * WW + xc0; s.i01 = yc0 * WW + xc1;
    s.i10 = yc1 * WW + xc0; s.i11 = yc1 * WW + xc1;
    float omwx = 1.0f - wx, omwy = 1.0f - wy;
    s.w00 = (xv0 && yv0) ? omwx * omwy : 0.0f;
    s.w01 = (xv1 && yv0) ? wx * omwy   : 0.0f;
    s.w10 = (xv0 && yv1) ? omwx * wy   : 0.0f;
    s.w11 = (xv1 && yv1) ? wx * wy     : 0.0f;
    return s;
}

// init: disp0 = eps*vel (fp16 interleaved) ; ldjac0 = logdet series (fp16). 1 px/thread.
__global__ void __launch_bounds__(256) init_kernel(const float* __restrict__ vel,
                                                   f16x2* __restrict__ ddst,
                                                   f16* __restrict__ ldst) {
    int idx = blockIdx.x * 256 + threadIdx.x;
    int n = idx >> 18;
    int rem = idx & (HW - 1);
    int y = rem >> 9, x = rem & (WW - 1);

    const float* v0 = vel + (size_t)n * 2 * HW;  // vel_y
    const float* v1 = v0 + HW;                   // vel_x

    float c0 = v0[rem], c1 = v1[rem];
    f16x2 dd; dd.x = (f16)(EPS * c0); dd.y = (f16)(EPS * c1);
    ddst[(size_t)n * HW + rem] = dd;

    int ym = max(y - 1, 0), yp = min(y + 1, HH - 1);
    int xm = max(x - 1, 0), xp = min(x + 1, WW - 1);
    int rmm = ym * WW + xm, rm0 = ym * WW + x, rmp = ym * WW + xp;
    int r0m = y * WW + xm,                    r0p = y * WW + xp;
    int rpm = yp * WW + xm, rp0 = yp * WW + x, rpp = yp * WW + xp;

    float a, b, c, d;
    {
        float tmm = v0[rmm], tm0 = v0[rm0], tmp = v0[rmp];
        float t0m = v0[r0m],                t0p = v0[r0p];
        float tpm = v0[rpm], tp0 = v0[rp0], tpp = v0[rpp];
        a = 0.125f * ((tpm + 2.0f * tp0 + tpp) - (tmm + 2.0f * tm0 + tmp));
        b = 0.125f * ((tmp + 2.0f * t0p + tpp) - (tmm + 2.0f * t0m + tpm));
    }
    {
        float tmm = v1[rmm], tm0 = v1[rm0], tmp = v1[rmp];
        float t0m = v1[r0m],                t0p = v1[r0p];
        float tpm = v1[rpm], tp0 = v1[rp0], tpp = v1[rpp];
        c = 0.125f * ((tpm + 2.0f * tp0 + tpp) - (tmm + 2.0f * tm0 + tmp));
        d = 0.125f * ((tmp + 2.0f * t0p + tpp) - (tmm + 2.0f * t0m + tpm));
    }

    float xa = a, xb = b, xc = c, xd = d;
    float ld = EPS * (xa + xd);
    float na = xa * a + xb * c, nb = xa * b + xb * d;
    float nc = xc * a + xd * c, nd = xc * b + xd * d;
    xa = na; xb = nb; xc = nc; xd = nd;
    ld -= (EPS * EPS) * (xa + xd) * 0.5f;
    na = xa * a + xb * c; nb = xa * b + xb * d;
    nc = xc * a + xd * c; nd = xc * b + xd * d;
    xa = na; xb = nb; xc = nc; xd = nd;
    ld += (EPS * EPS * EPS) * (xa + xd) * (1.0f / 3.0f);
    na = xa * a + xb * c;
    nd = xc * b + xd * d;
    ld -= (EPS * EPS * EPS * EPS) * (na + nd) * 0.25f;

    ldst[(size_t)n * HW + rem] = (f16)ld;
}

// one composition step, 2 px/thread (x even: pixels x and x+1), XCD-remapped.
//   disp_new(p)  = disp(p)  + bilerp(disp,  p + disp(p))
//   ldjac_new(p) = ldjac(p) + bilerp(ldjac, p + disp_new(p))
template <bool FINAL>
__global__ void __launch_bounds__(256) step_kernel(const f16x2* __restrict__ dsrc,
                                                   const f16* __restrict__ lsrc,
                                                   f16x2* __restrict__ ddst,
                                                   f16* __restrict__ ldst,
                                                   float* __restrict__ doutp,
                                                   float* __restrict__ loutp) {
    // 8192 blocks; XCD c (= bid&7) owns tasks [c*1024,(c+1)*1024) = images {2c,2c+1}.
    int bid = blockIdx.x;
    int task = ((bid & 7) << 10) | (bid >> 3);
    int tid = task * 256 + threadIdx.x;
    int pix = tid * 2;
    int n = pix >> 18;
    int rem = pix & (HW - 1);
    int y = rem >> 9, x = rem & (WW - 1);   // x even

    const f16x2* dp = dsrc + (size_t)n * HW;
    const f16*   lp = lsrc + (size_t)n * HW;

    // streaming loads for both pixels
    f16x4 dv = *(const f16x4*)(dp + rem);   // (dy0,dx0, dy1,dx1)
    f16x2 lv = *(const f16x2*)(lp + rem);

    float d0a = (float)dv.x, d1a = (float)dv.y;
    float d0b = (float)dv.z, d1b = (float)dv.w;

    // --- disp gathers: two independent chains ---
    float sya = fmaf((float)y + d0a, SC, -0.5f);
    float sxa = fmaf((float)x + d1a, SC, -0.5f);
    Samp sa = make_samp(sya, sxa);

    float syb = fmaf((float)y + d0b, SC, -0.5f);
    float sxb = fmaf((float)(x + 1) + d1b, SC, -0.5f);
    Samp sb = make_samp(syb, sxb);

    f16x2 a00 = dp[sa.i00], a01 = dp[sa.i01], a10 = dp[sa.i10], a11 = dp[sa.i11];
    f16x2 b00 = dp[sb.i00], b01 = dp[sb.i01], b10 = dp[sb.i10], b11 = dp[sb.i11];

    float nd0a = d0a + sa.w00 * (float)a00.x + sa.w01 * (float)a01.x
                     + sa.w10 * (float)a10.x + sa.w11 * (float)a11.x;
    float nd1a = d1a + sa.w00 * (float)a00.y + sa.w01 * (float)a01.y
                     + sa.w10 * (float)a10.y + sa.w11 * (float)a11.y;
    float nd0b = d0b + sb.w00 * (float)b00.x + sb.w01 * (float)b01.x
                     + sb.w10 * (float)b10.x + sb.w11 * (float)b11.x;
    float nd1b = d1b + sb.w00 * (float)b00.y + sb.w01 * (float)b01.y
                     + sb.w10 * (float)b10.y + sb.w11 * (float)b11.y;

    if (FINAL) {
        float* pd = doutp + (size_t)n * 2 * HW;
        f32x2 wy2; wy2.x = nd0a; wy2.y = nd0b;
        f32x2 wx2; wx2.x = nd1a; wx2.y = nd1b;
        *(f32x2*)(pd + rem) = wy2;
        *(f32x2*)(pd + HW + rem) = wx2;
    } else {
        f16x4 w; w.x = (f16)nd0a; w.y = (f16)nd1a; w.z = (f16)nd0b; w.w = (f16)nd1b;
        *(f16x4*)(ddst + (size_t)n * HW + rem) = w;
    }

    // --- ldjac gathers (depend on nd), two independent chains ---
    float sy2a = fmaf((float)y + nd0a, SC, -0.5f);
    float sx2a = fmaf((float)x + nd1a, SC, -0.5f);
    Samp ta = make_samp(sy2a, sx2a);

    float sy2b = fmaf((float)y + nd0b, SC, -0.5f);
    float sx2b = fmaf((float)(x + 1) + nd1b, SC, -0.5f);
    Samp tb = make_samp(sy2b, sx2b);

    float nla = (float)lv.x + ta.w00 * (float)lp[ta.i00] + ta.w01 * (float)lp[ta.i01]
                            + ta.w10 * (float)lp[ta.i10] + ta.w11 * (float)lp[ta.i11];
    float nlb = (float)lv.y + tb.w00 * (float)lp[tb.i00] + tb.w01 * (float)lp[tb.i01]
                            + tb.w10 * (float)lp[tb.i10] + tb.w11 * (float)lp[tb.i11];

    if (FINAL) {
        f32x2 nl2; nl2.x = nla; nl2.y = nlb;
        *(f32x2*)(loutp + (size_t)n * HW + rem) = nl2;
    } else {
        f16x2 wl; wl.x = (f16)nla; wl.y = (f16)nlb;
        *(f16x2*)(ldst + (size_t)n * HW + rem) = wl;
    }
}

extern "C" void kernel_launch(void* const* d_in, const int* in_sizes, int n_in,
                              void* d_out, int out_size, void* d_ws, size_t ws_size,
                              hipStream_t stream) {
    const float* vel = (const float*)d_in[0];
    float* out = (float*)d_out;

    // fp16 scratch set A in d_out raw bytes (24MB of 48MB), set B in ws.
    f16*   baseA = (f16*)d_out;
    f16*   baseB = (f16*)d_ws;
    f16x2* dA = (f16x2*)baseA;            // 8388608 halfs = 16MB
    f16*   lA = baseA + (size_t)2 * TOT;  // 4194304 halfs = 8MB
    f16x2* dB = (f16x2*)baseB;
    f16*   lB = baseB + (size_t)2 * TOT;

    dim3 block(256);
    dim3 grid_init(TOT / 256);        // 16384 blocks, 1 px/thread
    dim3 grid_step(TOT / 2 / 256);    // 8192 blocks, 2 px/thread

    // init -> B ; s0:B->A s1:A->B s2:B->A s3:A->B s4:B->A s5:A->B ; final:B->f32 d_out
    init_kernel<<<grid_init, block, 0, stream>>>(vel, dB, lB);

    const f16x2* ds = dB;
    const f16*   ls = lB;
    for (int s = 0; s < 6; ++s) {
        f16x2* dd  = (s & 1) ? dB : dA;
        f16*   ldd = (s & 1) ? lB : lA;
        step_kernel<false><<<grid_step, block, 0, stream>>>(ds, ls, dd, ldd, nullptr, nullptr);
        ds = dd; ls = ldd;
    }
    step_kernel<true><<<grid_step, block, 0, stream>>>(ds, ls, nullptr, nullptr,
                                                       out, out + DISP_ELEMS);
}

// Round 9
// 140.553 us; speedup vs baseline: 1.1971x; 1.1971x over previous
//
#include <hip/hip_runtime.h>

// Integrator (scaling & squaring) for vel [16,2,512,512] f32, with logdet-Jacobian.
// disp fp16 interleaved [N,HW,2] (4B/px), ldjac f32 [N,HW]. 1 px/thread,
// XCD-remapped steps, ping-pong. ROUND-9: pair-gathers — each bilinear corner
// row-pair (cols xc0,xc0+1) fetched with ONE 8B load + cndmask select, so
// gather VMEM instrs per px drop 8 -> 4 (attacks TA address-throughput bound).
// Scratch sets (32MB each): A = d_out raw bytes, B = ws.

#define NB 16
#define HH 512
#define WW 512
#define HW (HH * WW)          // 262144 = 1<<18
#define TOT (NB * HW)         // 4194304
#define EPS 0.0078125f        // 2^-7
#define DISP_ELEMS (NB * 2 * HW)   // 8388608 (f32 elems of final planar disp)
#define SC (512.0f / 511.0f)

typedef _Float16 f16;
typedef _Float16 f16x2 __attribute__((ext_vector_type(2)));

// sample descriptor for pair-gather: rows rlo/rhi, window col w (pair w,w+1),
// column selects, and OOB-folded bilinear weights.
struct Samp {
    int rlo, rhi, w;
    bool hi0, hi1;            // col select for xc0 / xc1 within the pair
    float w00, w01, w10, w11;
};

__device__ __forceinline__ Samp make_samp(float sy, float sx) {
    float fy = floorf(sy), fx = floorf(sx);
    float wy = sy - fy, wx = sx - fx;
    int y0 = (int)fy, x0 = (int)fx;
    int y1 = y0 + 1;
    bool xv0 = (unsigned)x0 < (unsigned)WW;
    bool xv1 = (unsigned)(x0 + 1) < (unsigned)WW;
    bool yv0 = (unsigned)y0 < (unsigned)HH;
    bool yv1 = (unsigned)y1 < (unsigned)HH;
    Samp s;
    s.rlo = min(max(y0, 0), HH - 1);
    s.rhi = min(max(y1, 0), HH - 1);
    s.w   = min(max(x0, 0), WW - 2);
    s.hi0 = (x0 > WW - 2);    // xc0 clamps to 511 -> high elem of pair
    s.hi1 = (x0 >= 0);        // xc1 = x0+1 -> high elem unless x0 < 0
    float omwx = 1.0f - wx, omwy = 1.0f - wy;
    s.w00 = (xv0 && yv0) ? omwx * omwy : 0.0f;
    s.w01 = (xv1 && yv0) ? wx * omwy   : 0.0f;
    s.w10 = (xv0 && yv1) ? omwx * wy   : 0.0f;
    s.w11 = (xv1 && yv1) ? wx * wy     : 0.0f;
    return s;
}

// fetch disp pair (cols w,w+1) from one row with a single 8B load; select cols.
__device__ __forceinline__ void pair_h(const f16x2* __restrict__ dp, int row, const Samp& s,
                                       f16x2& c0, f16x2& c1) {
    f16x2 pr[2];
    __builtin_memcpy(&pr, dp + row * WW + s.w, 8);
    c0 = s.hi0 ? pr[1] : pr[0];
    c1 = s.hi1 ? pr[1] : pr[0];
}

// fetch ldjac (f32) pair from one row with a single 8B load; select cols.
__device__ __forceinline__ void pair_f(const float* __restrict__ lp, int row, const Samp& s,
                                       float& c0, float& c1) {
    float pr[2];
    __builtin_memcpy(&pr, lp + row * WW + s.w, 8);
    c0 = s.hi0 ? pr[1] : pr[0];
    c1 = s.hi1 ? pr[1] : pr[0];
}

// init: disp0 = eps*vel (fp16 interleaved) ; ldjac0 = logdet series (f32). 1 px/thread.
__global__ void __launch_bounds__(256) init_kernel(const float* __restrict__ vel,
                                                   f16x2* __restrict__ ddst,
                                                   float* __restrict__ ldst) {
    int idx = blockIdx.x * 256 + threadIdx.x;
    int n = idx >> 18;
    int rem = idx & (HW - 1);
    int y = rem >> 9, x = rem & (WW - 1);

    const float* v0 = vel + (size_t)n * 2 * HW;  // vel_y
    const float* v1 = v0 + HW;                   // vel_x

    float c0 = v0[rem], c1 = v1[rem];
    f16x2 dd; dd.x = (f16)(EPS * c0); dd.y = (f16)(EPS * c1);
    ddst[(size_t)n * HW + rem] = dd;

    int ym = max(y - 1, 0), yp = min(y + 1, HH - 1);
    int xm = max(x - 1, 0), xp = min(x + 1, WW - 1);
    int rmm = ym * WW + xm, rm0 = ym * WW + x, rmp = ym * WW + xp;
    int r0m = y * WW + xm,                    r0p = y * WW + xp;
    int rpm = yp * WW + xm, rp0 = yp * WW + x, rpp = yp * WW + xp;

    float a, b, c, d;
    {
        float tmm = v0[rmm], tm0 = v0[rm0], tmp = v0[rmp];
        float t0m = v0[r0m],                t0p = v0[r0p];
        float tpm = v0[rpm], tp0 = v0[rp0], tpp = v0[rpp];
        a = 0.125f * ((tpm + 2.0f * tp0 + tpp) - (tmm + 2.0f * tm0 + tmp));
        b = 0.125f * ((tmp + 2.0f * t0p + tpp) - (tmm + 2.0f * t0m + tpm));
    }
    {
        float tmm = v1[rmm], tm0 = v1[rm0], tmp = v1[rmp];
        float t0m = v1[r0m],                t0p = v1[r0p];
        float tpm = v1[rpm], tp0 = v1[rp0], tpp = v1[rpp];
        c = 0.125f * ((tpm + 2.0f * tp0 + tpp) - (tmm + 2.0f * tm0 + tmp));
        d = 0.125f * ((tmp + 2.0f * t0p + tpp) - (tmm + 2.0f * t0m + tpm));
    }

    float xa = a, xb = b, xc = c, xd = d;
    float ld = EPS * (xa + xd);
    float na = xa * a + xb * c, nb = xa * b + xb * d;
    float nc = xc * a + xd * c, nd = xc * b + xd * d;
    xa = na; xb = nb; xc = nc; xd = nd;
    ld -= (EPS * EPS) * (xa + xd) * 0.5f;
    na = xa * a + xb * c; nb = xa * b + xb * d;
    nc = xc * a + xd * c; nd = xc * b + xd * d;
    xa = na; xb = nb; xc = nc; xd = nd;
    ld += (EPS * EPS * EPS) * (xa + xd) * (1.0f / 3.0f);
    na = xa * a + xb * c;
    nd = xc * b + xd * d;
    ld -= (EPS * EPS * EPS * EPS) * (na + nd) * 0.25f;

    ldst[(size_t)n * HW + rem] = ld;
}

// one composition step, 1 px/thread, XCD-remapped, pair-gathers.
//   disp_new(p)  = disp(p)  + bilerp(disp,  p + disp(p))
//   ldjac_new(p) = ldjac(p) + bilerp(ldjac, p + disp_new(p))
template <bool FINAL>
__global__ void __launch_bounds__(256) step_kernel(const f16x2* __restrict__ dsrc,
                                                   const float* __restrict__ lsrc,
                                                   f16x2* __restrict__ ddst,
                                                   float* __restrict__ ldst,
                                                   float* __restrict__ doutp,
                                                   float* __restrict__ loutp) {
    // 16384 tasks; XCD c (= bid&7) owns tasks [c*2048,(c+1)*2048) = images {2c,2c+1}.
    int bid = blockIdx.x;
    int task = ((bid & 7) << 11) | (bid >> 3);
    int idx = task * 256 + threadIdx.x;
    int n = idx >> 18;
    int rem = idx & (HW - 1);
    int y = rem >> 9, x = rem & (WW - 1);

    const f16x2* dp = dsrc + (size_t)n * HW;
    const float* lp = lsrc + (size_t)n * HW;

    f16x2 dv = dp[rem];
    float d0 = (float)dv.x, d1 = (float)dv.y;

    float sy = fmaf((float)y + d0, SC, -0.5f);
    float sx = fmaf((float)x + d1, SC, -0.5f);
    Samp s = make_samp(sy, sx);

    f16x2 r0c0, r0c1, r1c0, r1c1;
    pair_h(dp, s.rlo, s, r0c0, r0c1);
    pair_h(dp, s.rhi, s, r1c0, r1c1);

    float nd0 = d0 + s.w00 * (float)r0c0.x + s.w01 * (float)r0c1.x
                   + s.w10 * (float)r1c0.x + s.w11 * (float)r1c1.x;
    float nd1 = d1 + s.w00 * (float)r0c0.y + s.w01 * (float)r0c1.y
                   + s.w10 * (float)r1c0.y + s.w11 * (float)r1c1.y;

    if (FINAL) {
        float* pd = doutp + (size_t)n * 2 * HW;
        pd[rem] = nd0;
        pd[HW + rem] = nd1;
    } else {
        f16x2 w; w.x = (f16)nd0; w.y = (f16)nd1;
        ddst[(size_t)n * HW + rem] = w;
    }

    // ldjac sampled with the NEW disp at this pixel
    float sy2 = fmaf((float)y + nd0, SC, -0.5f);
    float sx2 = fmaf((float)x + nd1, SC, -0.5f);
    Samp t = make_samp(sy2, sx2);

    float l = lp[rem];
    float q0c0, q0c1, q1c0, q1c1;
    pair_f(lp, t.rlo, t, q0c0, q0c1);
    pair_f(lp, t.rhi, t, q1c0, q1c1);

    float nl = l + t.w00 * q0c0 + t.w01 * q0c1 + t.w10 * q1c0 + t.w11 * q1c1;

    if (FINAL) {
        loutp[(size_t)n * HW + rem] = nl;
    } else {
        ldst[(size_t)n * HW + rem] = nl;
    }
}

extern "C" void kernel_launch(void* const* d_in, const int* in_sizes, int n_in,
                              void* d_out, int out_size, void* d_ws, size_t ws_size,
                              hipStream_t stream) {
    const float* vel = (const float*)d_in[0];
    float* out = (float*)d_out;

    // Scratch set A in d_out raw bytes: disp fp16 16MB + ldjac f32 16MB = 32MB (of 48MB).
    // Set B in ws, same layout.
    f16x2* dA = (f16x2*)d_out;
    float* lA = (float*)((char*)d_out + (size_t)TOT * 4);
    f16x2* dB = (f16x2*)d_ws;
    float* lB = (float*)((char*)d_ws + (size_t)TOT * 4);

    dim3 grid(TOT / 256), block(256);     // 16384 blocks, 1 px/thread

    // init -> B ; s0:B->A s1:A->B s2:B->A s3:A->B s4:B->A s5:A->B ; final:B->f32 d_out
    init_kernel<<<grid, block, 0, stream>>>(vel, dB, lB);

    const f16x2* ds = dB;
    const float* ls = lB;
    for (int s = 0; s < 6; ++s) {
        f16x2* dd  = (s & 1) ? dB : dA;
        float* ldd = (s & 1) ? lB : lA;
        step_kernel<false><<<grid, block, 0, stream>>>(ds, ls, dd, ldd, nullptr, nullptr);
        ds = dd; ls = ldd;
    }
    step_kernel<true><<<grid, block, 0, stream>>>(ds, ls, nullptr, nullptr,
                                                  out, out + DISP_ELEMS);
}

// Round 10
// 137.132 us; speedup vs baseline: 1.2270x; 1.0249x over previous
//
#include <hip/hip_runtime.h>

// Integrator (scaling & squaring) for vel [16,2,512,512] f32, with logdet-Jacobian.
// ROUND-10: decoupled ldjac update. Kernel K_k streams disp_k and computes BOTH
//   disp_{k+1}(p) = disp_k(p) + bilerp(disp_k, phi(p, disp_k(p)))
//   ldjac_k(p)    = ldjac_{k-1}(p) + bilerp(ldjac_{k-1}, phi(p, disp_k(p)))
// Same sample position for both -> ONE make_samp, 8 parallel gathers, single
// dependent memory round (was two serial rounds). fp16 disp interleaved
// [N,HW,2] + fp16 ldjac [N,HW]; XCD-remapped; all scratch in ws (48MB):
//   dB 16MB | dC 16MB | lB 8MB | lA 8MB.  d_out written only by FINAL.
// Dispatches: init -> K1(disp-only) -> K2..K7(full) -> FINAL(ldjac7 + planar f32).

#define NB 16
#define HH 512
#define WW 512
#define HW (HH * WW)          // 262144 = 1<<18
#define TOT (NB * HW)         // 4194304
#define EPS 0.0078125f        // 2^-7
#define DISP_ELEMS (NB * 2 * HW)   // 8388608 (f32 elems of final planar disp)
#define SC (512.0f / 511.0f)

typedef _Float16 f16;
typedef _Float16 f16x2 __attribute__((ext_vector_type(2)));

struct Samp {
    int i00, i01, i10, i11;   // clamped plane offsets (y*W+x)
    float w00, w01, w10, w11; // bilinear weights with OOB folded to 0
};

__device__ __forceinline__ Samp make_samp(float sy, float sx) {
    float fy = floorf(sy), fx = floorf(sx);
    float wy = sy - fy, wx = sx - fx;
    int y0 = (int)fy, x0 = (int)fx;
    int y1 = y0 + 1, x1 = x0 + 1;
    bool xv0 = (unsigned)x0 < (unsigned)WW;
    bool xv1 = (unsigned)x1 < (unsigned)WW;
    bool yv0 = (unsigned)y0 < (unsigned)HH;
    bool yv1 = (unsigned)y1 < (unsigned)HH;
    int xc0 = min(max(x0, 0), WW - 1), xc1 = min(max(x1, 0), WW - 1);
    int yc0 = min(max(y0, 0), HH - 1), yc1 = min(max(y1, 0), HH - 1);
    Samp s;
    s.i00 = yc0 * WW + xc0; s.i01 = yc0 * WW + xc1;
    s.i10 = yc1 * WW + xc0; s.i11 = yc1 * WW + xc1;
    float omwx = 1.0f - wx, omwy = 1.0f - wy;
    s.w00 = (xv0 && yv0) ? omwx * omwy : 0.0f;
    s.w01 = (xv1 && yv0) ? wx * omwy   : 0.0f;
    s.w10 = (xv0 && yv1) ? omwx * wy   : 0.0f;
    s.w11 = (xv1 && yv1) ? wx * wy     : 0.0f;
    return s;
}

// init: disp0 = eps*vel (fp16 interleaved) ; ldjac0 = logdet series (fp16). 1 px/thread.
__global__ void __launch_bounds__(256) init_kernel(const float* __restrict__ vel,
                                                   f16x2* __restrict__ ddst,
                                                   f16* __restrict__ ldst) {
    int idx = blockIdx.x * 256 + threadIdx.x;
    int n = idx >> 18;
    int rem = idx & (HW - 1);
    int y = rem >> 9, x = rem & (WW - 1);

    const float* v0 = vel + (size_t)n * 2 * HW;  // vel_y
    const float* v1 = v0 + HW;                   // vel_x

    float c0 = v0[rem], c1 = v1[rem];
    f16x2 dd; dd.x = (f16)(EPS * c0); dd.y = (f16)(EPS * c1);
    ddst[(size_t)n * HW + rem] = dd;

    int ym = max(y - 1, 0), yp = min(y + 1, HH - 1);
    int xm = max(x - 1, 0), xp = min(x + 1, WW - 1);
    int rmm = ym * WW + xm, rm0 = ym * WW + x, rmp = ym * WW + xp;
    int r0m = y * WW + xm,                    r0p = y * WW + xp;
    int rpm = yp * WW + xm, rp0 = yp * WW + x, rpp = yp * WW + xp;

    float a, b, c, d;
    {
        float tmm = v0[rmm], tm0 = v0[rm0], tmp = v0[rmp];
        float t0m = v0[r0m],                t0p = v0[r0p];
        float tpm = v0[rpm], tp0 = v0[rp0], tpp = v0[rpp];
        a = 0.125f * ((tpm + 2.0f * tp0 + tpp) - (tmm + 2.0f * tm0 + tmp));
        b = 0.125f * ((tmp + 2.0f * t0p + tpp) - (tmm + 2.0f * t0m + tpm));
    }
    {
        float tmm = v1[rmm], tm0 = v1[rm0], tmp = v1[rmp];
        float t0m = v1[r0m],                t0p = v1[r0p];
        float tpm = v1[rpm], tp0 = v1[rp0], tpp = v1[rpp];
        c = 0.125f * ((tpm + 2.0f * tp0 + tpp) - (tmm + 2.0f * tm0 + tmp));
        d = 0.125f * ((tmp + 2.0f * t0p + tpp) - (tmm + 2.0f * t0m + tpm));
    }

    float xa = a, xb = b, xc = c, xd = d;
    float ld = EPS * (xa + xd);
    float na = xa * a + xb * c, nb = xa * b + xb * d;
    float nc = xc * a + xd * c, nd = xc * b + xd * d;
    xa = na; xb = nb; xc = nc; xd = nd;
    ld -= (EPS * EPS) * (xa + xd) * 0.5f;
    na = xa * a + xb * c; nb = xa * b + xb * d;
    nc = xc * a + xd * c; nd = xc * b + xd * d;
    xa = na; xb = nb; xc = nc; xd = nd;
    ld += (EPS * EPS * EPS) * (xa + xd) * (1.0f / 3.0f);
    na = xa * a + xb * c;
    nd = xc * b + xd * d;
    ld -= (EPS * EPS * EPS * EPS) * (na + nd) * 0.25f;

    ldst[(size_t)n * HW + rem] = (f16)ld;
}

// XCD-remapped index helper: XCD c (= bid&7) owns tasks [c*2048,(c+1)*2048)
// = images {2c,2c+1}, rows ascending.
__device__ __forceinline__ int remap_idx() {
    int bid = blockIdx.x;
    int task = ((bid & 7) << 11) | (bid >> 3);
    return task * 256 + threadIdx.x;
}

// K1: disp update only (ldjac buffer passes through untouched).
__global__ void __launch_bounds__(256) step_disp(const f16x2* __restrict__ dsrc,
                                                 f16x2* __restrict__ ddst) {
    int idx = remap_idx();
    int n = idx >> 18;
    int rem = idx & (HW - 1);
    int y = rem >> 9, x = rem & (WW - 1);

    const f16x2* dp = dsrc + (size_t)n * HW;
    f16x2 dv = dp[rem];
    float d0 = (float)dv.x, d1 = (float)dv.y;

    float sy = fmaf((float)y + d0, SC, -0.5f);
    float sx = fmaf((float)x + d1, SC, -0.5f);
    Samp s = make_samp(sy, sx);

    f16x2 g00 = dp[s.i00], g01 = dp[s.i01], g10 = dp[s.i10], g11 = dp[s.i11];
    float nd0 = d0 + s.w00 * (float)g00.x + s.w01 * (float)g01.x
                   + s.w10 * (float)g10.x + s.w11 * (float)g11.x;
    float nd1 = d1 + s.w00 * (float)g00.y + s.w01 * (float)g01.y
                   + s.w10 * (float)g10.y + s.w11 * (float)g11.y;

    f16x2 w; w.x = (f16)nd0; w.y = (f16)nd1;
    ddst[(size_t)n * HW + rem] = w;
}

// K2..K7: disp_{k+1} AND ldjac_k, both sampled at phi(p, disp_k(p)) — one samp,
// 8 parallel gathers (4 disp + 4 ldjac), single dependent memory round.
__global__ void __launch_bounds__(256) step_full(const f16x2* __restrict__ dsrc,
                                                 const f16* __restrict__ lsrc,
                                                 f16x2* __restrict__ ddst,
                                                 f16* __restrict__ ldst) {
    int idx = remap_idx();
    int n = idx >> 18;
    int rem = idx & (HW - 1);
    int y = rem >> 9, x = rem & (WW - 1);

    const f16x2* dp = dsrc + (size_t)n * HW;
    const f16*   lp = lsrc + (size_t)n * HW;

    f16x2 dv = dp[rem];
    f16   lv = lp[rem];
    float d0 = (float)dv.x, d1 = (float)dv.y;

    float sy = fmaf((float)y + d0, SC, -0.5f);
    float sx = fmaf((float)x + d1, SC, -0.5f);
    Samp s = make_samp(sy, sx);

    // all 8 gathers independent, same indices
    f16x2 g00 = dp[s.i00], g01 = dp[s.i01], g10 = dp[s.i10], g11 = dp[s.i11];
    f16   h00 = lp[s.i00], h01 = lp[s.i01], h10 = lp[s.i10], h11 = lp[s.i11];

    float nd0 = d0 + s.w00 * (float)g00.x + s.w01 * (float)g01.x
                   + s.w10 * (float)g10.x + s.w11 * (float)g11.x;
    float nd1 = d1 + s.w00 * (float)g00.y + s.w01 * (float)g01.y
                   + s.w10 * (float)g10.y + s.w11 * (float)g11.y;
    float nl  = (float)lv + s.w00 * (float)h00 + s.w01 * (float)h01
                          + s.w10 * (float)h10 + s.w11 * (float)h11;

    f16x2 w; w.x = (f16)nd0; w.y = (f16)nd1;
    ddst[(size_t)n * HW + rem] = w;
    ldst[(size_t)n * HW + rem] = (f16)nl;
}

// FINAL: ldjac update #7 using streamed disp_7 (no disp gathers), plus planar
// f32 output of disp_7 and ldjac_7.
__global__ void __launch_bounds__(256) step_final(const f16x2* __restrict__ dsrc,
                                                  const f16* __restrict__ lsrc,
                                                  float* __restrict__ doutp,
                                                  float* __restrict__ loutp) {
    int idx = remap_idx();
    int n = idx >> 18;
    int rem = idx & (HW - 1);
    int y = rem >> 9, x = rem & (WW - 1);

    const f16x2* dp = dsrc + (size_t)n * HW;
    const f16*   lp = lsrc + (size_t)n * HW;

    f16x2 dv = dp[rem];
    f16   lv = lp[rem];
    float d0 = (float)dv.x, d1 = (float)dv.y;

    float sy = fmaf((float)y + d0, SC, -0.5f);
    float sx = fmaf((float)x + d1, SC, -0.5f);
    Samp s = make_samp(sy, sx);

    float nl = (float)lv + s.w00 * (float)lp[s.i00] + s.w01 * (float)lp[s.i01]
                         + s.w10 * (float)lp[s.i10] + s.w11 * (float)lp[s.i11];

    float* pd = doutp + (size_t)n * 2 * HW;
    pd[rem]      = d0;
    pd[HW + rem] = d1;
    loutp[(size_t)n * HW + rem] = nl;
}

extern "C" void kernel_launch(void* const* d_in, const int* in_sizes, int n_in,
                              void* d_out, int out_size, void* d_ws, size_t ws_size,
                              hipStream_t stream) {
    const float* vel = (const float*)d_in[0];
    float* out = (float*)d_out;

    // ws layout (48MB): dB 16MB | dC 16MB | lB 8MB | lA 8MB
    char* wsb = (char*)d_ws;
    f16x2* dB = (f16x2*)wsb;
    f16x2* dC = (f16x2*)(wsb + (size_t)16 * 1024 * 1024);
    f16*   lB = (f16*)  (wsb + (size_t)32 * 1024 * 1024);
    f16*   lA = (f16*)  (wsb + (size_t)40 * 1024 * 1024);

    dim3 grid(TOT / 256), block(256);     // 16384 blocks, 1 px/thread

    // init       -> (dB, lB)            : disp0, ldjac0
    // K1  disp   : dB -> dC             : disp1
    // K2  full   : (dC, lB) -> (dB, lA) : disp2, ldjac1
    // K3  full   : (dB, lA) -> (dC, lB) : disp3, ldjac2
    // K4  full   : (dC, lB) -> (dB, lA) : disp4, ldjac3
    // K5  full   : (dB, lA) -> (dC, lB) : disp5, ldjac4
    // K6  full   : (dC, lB) -> (dB, lA) : disp6, ldjac5
    // K7  full   : (dB, lA) -> (dC, lB) : disp7, ldjac6
    // FINAL      : (dC, lB) -> d_out    : planar f32 disp7 + f32 ldjac7
    init_kernel<<<grid, block, 0, stream>>>(vel, dB, lB);
    step_disp<<<grid, block, 0, stream>>>(dB, dC);
    step_full<<<grid, block, 0, stream>>>(dC, lB, dB, lA);
    step_full<<<grid, block, 0, stream>>>(dB, lA, dC, lB);
    step_full<<<grid, block, 0, stream>>>(dC, lB, dB, lA);
    step_full<<<grid, block, 0, stream>>>(dB, lA, dC, lB);
    step_full<<<grid, block, 0, stream>>>(dC, lB, dB, lA);
    step_full<<<grid, block, 0, stream>>>(dB, lA, dC, lB);
    step_final<<<grid, block, 0, stream>>>(dC, lB, out, out + DISP_ELEMS);
}

// Round 11
// 127.861 us; speedup vs baseline: 1.3160x; 1.0725x over previous
//
#include <hip/hip_runtime.h>

// Integrator (scaling & squaring) for vel [16,2,512,512] f32, with logdet-Jacobian.
// Decoupled ldjac schedule (round 10) + ROUND-11: init and the first disp step
// fused into one kernel (disp0 = eps*vel is pointwise, so K1's bilerp corners
// gather vel directly; fp16 rounding of disp0 emulated to keep numerics
// identical). 8 dispatches: INIT_FUSED -> K2..K7 (6x step_full) -> FINAL.
// fp16 disp interleaved [N,HW,2] + fp16 ldjac [N,HW]; XCD-remapped everywhere;
// scratch in ws (48MB): dB 16MB | dC 16MB | lB 8MB | lA 8MB. d_out only FINAL.

#define NB 16
#define HH 512
#define WW 512
#define HW (HH * WW)          // 262144 = 1<<18
#define TOT (NB * HW)         // 4194304
#define EPS 0.0078125f        // 2^-7
#define DISP_ELEMS (NB * 2 * HW)   // 8388608 (f32 elems of final planar disp)
#define SC (512.0f / 511.0f)

typedef _Float16 f16;
typedef _Float16 f16x2 __attribute__((ext_vector_type(2)));

struct Samp {
    int i00, i01, i10, i11;   // clamped plane offsets (y*W+x)
    float w00, w01, w10, w11; // bilinear weights with OOB folded to 0
};

__device__ __forceinline__ Samp make_samp(float sy, float sx) {
    float fy = floorf(sy), fx = floorf(sx);
    float wy = sy - fy, wx = sx - fx;
    int y0 = (int)fy, x0 = (int)fx;
    int y1 = y0 + 1, x1 = x0 + 1;
    bool xv0 = (unsigned)x0 < (unsigned)WW;
    bool xv1 = (unsigned)x1 < (unsigned)WW;
    bool yv0 = (unsigned)y0 < (unsigned)HH;
    bool yv1 = (unsigned)y1 < (unsigned)HH;
    int xc0 = min(max(x0, 0), WW - 1), xc1 = min(max(x1, 0), WW - 1);
    int yc0 = min(max(y0, 0), HH - 1), yc1 = min(max(y1, 0), HH - 1);
    Samp s;
    s.i00 = yc0 * WW + xc0; s.i01 = yc0 * WW + xc1;
    s.i10 = yc1 * WW + xc0; s.i11 = yc1 * WW + xc1;
    float omwx = 1.0f - wx, omwy = 1.0f - wy;
    s.w00 = (xv0 && yv0) ? omwx * omwy : 0.0f;
    s.w01 = (xv1 && yv0) ? wx * omwy   : 0.0f;
    s.w10 = (xv0 && yv1) ? omwx * wy   : 0.0f;
    s.w11 = (xv1 && yv1) ? wx * wy     : 0.0f;
    return s;
}

// XCD-remapped index: XCD c (= bid&7 under round-robin dispatch) owns tasks
// [c*2048,(c+1)*2048) = images {2c,2c+1}, rows ascending.
__device__ __forceinline__ int remap_idx() {
    int bid = blockIdx.x;
    int task = ((bid & 7) << 11) | (bid >> 3);
    return task * 256 + threadIdx.x;
}

// emulate the fp16 store+load rounding of disp0 = eps*v
__device__ __forceinline__ float rnd16(float v) { return (float)(f16)v; }

// INIT_FUSED: ldjac0 (sobel logdet series), disp1 = disp0 + bilerp(disp0, phi(p, disp0(p)))
// with disp0 = (f16)(eps*vel) gathered straight from vel. 1 px/thread.
__global__ void __launch_bounds__(256) init_fused(const float* __restrict__ vel,
                                                  f16x2* __restrict__ ddst,
                                                  f16* __restrict__ ldst) {
    int idx = remap_idx();
    int n = idx >> 18;
    int rem = idx & (HW - 1);
    int y = rem >> 9, x = rem & (WW - 1);

    const float* v0 = vel + (size_t)n * 2 * HW;  // vel_y
    const float* v1 = v0 + HW;                   // vel_x

    // ---- sobel jacobian + logdet series (ldjac0) ----
    int ym = max(y - 1, 0), yp = min(y + 1, HH - 1);
    int xm = max(x - 1, 0), xp = min(x + 1, WW - 1);
    int rmm = ym * WW + xm, rm0 = ym * WW + x, rmp = ym * WW + xp;
    int r0m = y * WW + xm,  r00 = y * WW + x,  r0p = y * WW + xp;
    int rpm = yp * WW + xm, rp0 = yp * WW + x, rpp = yp * WW + xp;

    float a, b, c, d;
    {
        float tmm = v0[rmm], tm0 = v0[rm0], tmp = v0[rmp];
        float t0m = v0[r0m],                t0p = v0[r0p];
        float tpm = v0[rpm], tp0 = v0[rp0], tpp = v0[rpp];
        a = 0.125f * ((tpm + 2.0f * tp0 + tpp) - (tmm + 2.0f * tm0 + tmp));
        b = 0.125f * ((tmp + 2.0f * t0p + tpp) - (tmm + 2.0f * t0m + tpm));
    }
    {
        float tmm = v1[rmm], tm0 = v1[rm0], tmp = v1[rmp];
        float t0m = v1[r0m],                t0p = v1[r0p];
        float tpm = v1[rpm], tp0 = v1[rp0], tpp = v1[rpp];
        c = 0.125f * ((tpm + 2.0f * tp0 + tpp) - (tmm + 2.0f * tm0 + tmp));
        d = 0.125f * ((tmp + 2.0f * t0p + tpp) - (tmm + 2.0f * t0m + tpm));
    }

    float xa = a, xb = b, xc = c, xd = d;
    float ld = EPS * (xa + xd);
    float na = xa * a + xb * c, nb = xa * b + xb * d;
    float nc = xc * a + xd * c, nd = xc * b + xd * d;
    xa = na; xb = nb; xc = nc; xd = nd;
    ld -= (EPS * EPS) * (xa + xd) * 0.5f;
    na = xa * a + xb * c; nb = xa * b + xb * d;
    nc = xc * a + xd * c; nd = xc * b + xd * d;
    xa = na; xb = nb; xc = nc; xd = nd;
    ld += (EPS * EPS * EPS) * (xa + xd) * (1.0f / 3.0f);
    na = xa * a + xb * c;
    nd = xc * b + xd * d;
    ld -= (EPS * EPS * EPS * EPS) * (na + nd) * 0.25f;

    ldst[(size_t)n * HW + rem] = (f16)ld;

    // ---- first disp step, corners gathered from vel ----
    float d0 = rnd16(EPS * v0[r00]);
    float d1 = rnd16(EPS * v1[r00]);

    float sy = fmaf((float)y + d0, SC, -0.5f);
    float sx = fmaf((float)x + d1, SC, -0.5f);
    Samp s = make_samp(sy, sx);

    float g00x = rnd16(EPS * v0[s.i00]), g00y = rnd16(EPS * v1[s.i00]);
    float g01x = rnd16(EPS * v0[s.i01]), g01y = rnd16(EPS * v1[s.i01]);
    float g10x = rnd16(EPS * v0[s.i10]), g10y = rnd16(EPS * v1[s.i10]);
    float g11x = rnd16(EPS * v0[s.i11]), g11y = rnd16(EPS * v1[s.i11]);

    float nd0 = d0 + s.w00 * g00x + s.w01 * g01x + s.w10 * g10x + s.w11 * g11x;
    float nd1 = d1 + s.w00 * g00y + s.w01 * g01y + s.w10 * g10y + s.w11 * g11y;

    f16x2 w; w.x = (f16)nd0; w.y = (f16)nd1;
    ddst[(size_t)n * HW + rem] = w;
}

// K2..K7: disp_{k+1} AND ldjac_k, both sampled at phi(p, disp_k(p)) — one samp,
// 8 parallel gathers (4 disp + 4 ldjac), single dependent memory round.
__global__ void __launch_bounds__(256) step_full(const f16x2* __restrict__ dsrc,
                                                 const f16* __restrict__ lsrc,
                                                 f16x2* __restrict__ ddst,
                                                 f16* __restrict__ ldst) {
    int idx = remap_idx();
    int n = idx >> 18;
    int rem = idx & (HW - 1);
    int y = rem >> 9, x = rem & (WW - 1);

    const f16x2* dp = dsrc + (size_t)n * HW;
    const f16*   lp = lsrc + (size_t)n * HW;

    f16x2 dv = dp[rem];
    f16   lv = lp[rem];
    float d0 = (float)dv.x, d1 = (float)dv.y;

    float sy = fmaf((float)y + d0, SC, -0.5f);
    float sx = fmaf((float)x + d1, SC, -0.5f);
    Samp s = make_samp(sy, sx);

    f16x2 g00 = dp[s.i00], g01 = dp[s.i01], g10 = dp[s.i10], g11 = dp[s.i11];
    f16   h00 = lp[s.i00], h01 = lp[s.i01], h10 = lp[s.i10], h11 = lp[s.i11];

    float nd0 = d0 + s.w00 * (float)g00.x + s.w01 * (float)g01.x
                   + s.w10 * (float)g10.x + s.w11 * (float)g11.x;
    float nd1 = d1 + s.w00 * (float)g00.y + s.w01 * (float)g01.y
                   + s.w10 * (float)g10.y + s.w11 * (float)g11.y;
    float nl  = (float)lv + s.w00 * (float)h00 + s.w01 * (float)h01
                          + s.w10 * (float)h10 + s.w11 * (float)h11;

    f16x2 w; w.x = (f16)nd0; w.y = (f16)nd1;
    ddst[(size_t)n * HW + rem] = w;
    ldst[(size_t)n * HW + rem] = (f16)nl;
}

// FINAL: ldjac update #7 using streamed disp_7 (no disp gathers), plus planar
// f32 output of disp_7 and ldjac_7.
__global__ void __launch_bounds__(256) step_final(const f16x2* __restrict__ dsrc,
                                                  const f16* __restrict__ lsrc,
                                                  float* __restrict__ doutp,
                                                  float* __restrict__ loutp) {
    int idx = remap_idx();
    int n = idx >> 18;
    int rem = idx & (HW - 1);
    int y = rem >> 9, x = rem & (WW - 1);

    const f16x2* dp = dsrc + (size_t)n * HW;
    const f16*   lp = lsrc + (size_t)n * HW;

    f16x2 dv = dp[rem];
    f16   lv = lp[rem];
    float d0 = (float)dv.x, d1 = (float)dv.y;

    float sy = fmaf((float)y + d0, SC, -0.5f);
    float sx = fmaf((float)x + d1, SC, -0.5f);
    Samp s = make_samp(sy, sx);

    float nl = (float)lv + s.w00 * (float)lp[s.i00] + s.w01 * (float)lp[s.i01]
                         + s.w10 * (float)lp[s.i10] + s.w11 * (float)lp[s.i11];

    float* pd = doutp + (size_t)n * 2 * HW;
    pd[rem]      = d0;
    pd[HW + rem] = d1;
    loutp[(size_t)n * HW + rem] = nl;
}

extern "C" void kernel_launch(void* const* d_in, const int* in_sizes, int n_in,
                              void* d_out, int out_size, void* d_ws, size_t ws_size,
                              hipStream_t stream) {
    const float* vel = (const float*)d_in[0];
    float* out = (float*)d_out;

    // ws layout (48MB): dB 16MB | dC 16MB | lB 8MB | lA 8MB
    char* wsb = (char*)d_ws;
    f16x2* dB = (f16x2*)wsb;
    f16x2* dC = (f16x2*)(wsb + (size_t)16 * 1024 * 1024);
    f16*   lB = (f16*)  (wsb + (size_t)32 * 1024 * 1024);
    f16*   lA = (f16*)  (wsb + (size_t)40 * 1024 * 1024);

    dim3 grid(TOT / 256), block(256);     // 16384 blocks, 1 px/thread

    // INIT_FUSED -> (dC = disp1, lB = ldjac0)
    // K2: (dC,lB)->(dB,lA)  disp2, ldjac1
    // K3: (dB,lA)->(dC,lB)  disp3, ldjac2
    // K4: (dC,lB)->(dB,lA)  disp4, ldjac3
    // K5: (dB,lA)->(dC,lB)  disp5, ldjac4
    // K6: (dC,lB)->(dB,lA)  disp6, ldjac5
    // K7: (dB,lA)->(dC,lB)  disp7, ldjac6
    // FINAL: (dC,lB) -> d_out (planar f32 disp7 + f32 ldjac7)
    init_fused<<<grid, block, 0, stream>>>(vel, dC, lB);
    step_full<<<grid, block, 0, stream>>>(dC, lB, dB, lA);
    step_full<<<grid, block, 0, stream>>>(dB, lA, dC, lB);
    step_full<<<grid, block, 0, stream>>>(dC, lB, dB, lA);
    step_full<<<grid, block, 0, stream>>>(dB, lA, dC, lB);
    step_full<<<grid, block, 0, stream>>>(dC, lB, dB, lA);
    step_full<<<grid, block, 0, stream>>>(dB, lA, dC, lB);
    step_final<<<grid, block, 0, stream>>>(dC, lB, out, out + DISP_ELEMS);
}